// Round 12
// baseline (235.139 us; speedup 1.0000x reference)
//
#include <hip/hip_runtime.h>
#include <math.h>

#define NN   10000          // nodes
#define NE   160000         // raw edges
#define NET  (NE + NN)      // edges + self loops = 170000
#define FIN  70
#define HIDC 256
#define NH   4
#define D1   1024           // NH*HIDC
#define SLOPE 0.2f
#define KL1  96             // K for layer-1 GEMM (70 padded to 96)
#define NPB  32             // pooling buckets
#define BCAP 64             // per-dst edge bucket capacity (deg mean 17, P(>63)~1e-15)

typedef float f32x4 __attribute__((ext_vector_type(4)));
typedef short bf16x8 __attribute__((ext_vector_type(8)));

__device__ __forceinline__ unsigned short f32_to_bf16(float f) {
    unsigned int u = __float_as_uint(f);
    unsigned int r = u + 0x7fffu + ((u >> 16) & 1u);   // round-to-nearest-even
    return (unsigned short)(r >> 16);
}
__device__ __forceinline__ float bf16_to_f32(unsigned short h) {
    return __uint_as_float(((unsigned int)h) << 16);
}
__device__ __forceinline__ float leaky(float e) { return (e > 0.f) ? e : SLOPE * e; }

// async 16B global->LDS DMA (m97-verified path; LDS dest = wave base + lane*16)
__device__ __forceinline__ void cp16(const unsigned short* g, unsigned short* l) {
    __builtin_amdgcn_global_load_lds((const __attribute__((address_space(1))) unsigned int*)g,
                                     (__attribute__((address_space(3))) unsigned int*)l,
                                     16, 0, 0);
}

// ---------------- fused prep: W2 conv | W1 conv | was/wad | x->bf16 | bucket scatter ----------------
// blocks: [0,1024) W2 ; [1024,1120) W1 ; [1120,1190) was/wad ; [1190,1230) xb ; [1230,1895) scatter
__global__ __launch_bounds__(256) void k_prep(const float* __restrict__ W2,
                                              unsigned short* __restrict__ W2t,
                                              const float* __restrict__ W1,
                                              unsigned short* __restrict__ W1t,
                                              const float* __restrict__ asrc,
                                              const float* __restrict__ adst,
                                              float* __restrict__ was,
                                              float* __restrict__ wad,
                                              const float* __restrict__ x,
                                              unsigned short* __restrict__ xb,
                                              const int* __restrict__ ei,
                                              int* __restrict__ cnt,
                                              int* __restrict__ ssrc) {
    int b = blockIdx.x, t = threadIdx.x;
    if (b < 1024) {
        int kk = b, n = t;
        W2t[(size_t)n * 1024 + kk] = f32_to_bf16(W2[(size_t)kk * HIDC + n]);
    } else if (b < 1024 + KL1) {
        int kk = b - 1024, n = t;
#pragma unroll
        for (int h = 0; h < NH; h++) {
            float w = (kk < FIN) ? W1[(size_t)kk * D1 + h * 256 + n] : 0.f;
            W1t[((size_t)(h * 256 + n)) * KL1 + kk] = f32_to_bf16(w);
        }
    } else if (b < 1024 + KL1 + FIN) {
        int k = b - 1024 - KL1;
        __shared__ float rs[256], rd[256];
#pragma unroll
        for (int h = 0; h < NH; h++) {
            float wv = W1[(size_t)k * D1 + h * 256 + t];
            rs[t] = wv * asrc[h * 256 + t];
            rd[t] = wv * adst[h * 256 + t];
            __syncthreads();
            for (int off = 128; off > 0; off >>= 1) {
                if (t < off) { rs[t] += rs[t + off]; rd[t] += rd[t + off]; }
                __syncthreads();
            }
            if (t == 0) { was[h * FIN + k] = rs[0]; wad[h * FIN + k] = rd[0]; }
            __syncthreads();
        }
    } else if (b < 1024 + KL1 + FIN + 40) {
        int b2 = b - 1024 - KL1 - FIN;                 // 0..39, 17500 elems each
        size_t base = (size_t)b2 * 17500;
        for (int i = t; i < 17500; i += 256)
            xb[base + i] = f32_to_bf16(x[base + i]);
    } else {
        int e = (b - 1024 - KL1 - FIN - 40) * 256 + t;
        if (e < NET) {
            int src, dst;
            if (e < NE) { src = ei[e]; dst = ei[NE + e]; }
            else        { src = e - NE; dst = src; }
            int pos = atomicAdd(&cnt[dst], 1);
            if (pos < BCAP) ssrc[dst * BCAP + pos] = src;
        }
    }
}

// ---------------- fused attention-logits + softmax(H=4) + layer-1 aggregation ----------------
// 1 wave per dst node; neighbor x-rows staged in LDS once, logits computed locally
__global__ __launch_bounds__(64) void k_sm_aggX(const int* __restrict__ cnt,
                                                const int* __restrict__ ssrc,
                                                const float* __restrict__ was,
                                                const float* __restrict__ wad,
                                                const unsigned short* __restrict__ xb,
                                                unsigned short* __restrict__ aggXhi) {
    int d = blockIdx.x, t = threadIdx.x;
    int n = cnt[d]; if (n > BCAP) n = BCAP;
    __shared__ unsigned short xs[64][74];   // 74-pad: stride 37 words, conflict-free column reads
    __shared__ float wl[NH][FIN];
    __shared__ float dl[NH][FIN];
    __shared__ float al4[64][4];
    __shared__ float advs[NH];
    __shared__ int sid[64];
    __shared__ int jd_sh;
    for (int i = t; i < NH * FIN; i += 64) {
        wl[i / FIN][i % FIN] = was[i];
        dl[i / FIN][i % FIN] = wad[i];
    }
    if (t < n) {
        int s0 = ssrc[d * BCAP + t];
        sid[t] = s0;
        if (s0 == d) jd_sh = t;             // self-loop always present
    }
    __syncthreads();
    // stage neighbor rows into LDS (coalesced per row)
    for (int j = 0; j < n; j++) {
        int s = sid[j];
        xs[j][t] = xb[(size_t)s * FIN + t];
        if (t < FIN - 64) xs[j][64 + t] = xb[(size_t)s * FIN + 64 + t];
    }
    __syncthreads();
    // dst-row attention dot: threads 0..3, one head each
    if (t < NH) {
        int jd = jd_sh;
        float a = 0.f;
        for (int k = 0; k < FIN; k++) a += bf16_to_f32(xs[jd][k]) * dl[t][k];
        advs[t] = a;
    }
    // per-neighbor src dots (thread j owns neighbor j)
    float a4[NH] = {};
    if (t < n) {
        for (int k = 0; k < FIN; k++) {
            float xv = bf16_to_f32(xs[t][k]);
#pragma unroll
            for (int h = 0; h < NH; h++) a4[h] += xv * wl[h][k];
        }
    }
    __syncthreads();
    bool v0 = t < n;
    float e0[NH], m[NH], sum[NH];
#pragma unroll
    for (int h = 0; h < NH; h++) e0[h] = v0 ? leaky(a4[h] + advs[h]) : -1e30f;
#pragma unroll
    for (int h = 0; h < NH; h++) {
        m[h] = e0[h];
        for (int off = 32; off > 0; off >>= 1) m[h] = fmaxf(m[h], __shfl_xor(m[h], off));
        sum[h] = v0 ? expf(e0[h] - m[h]) : 0.f;
        for (int off = 32; off > 0; off >>= 1) sum[h] += __shfl_xor(sum[h], off);
    }
    if (v0) {
#pragma unroll
        for (int h = 0; h < NH; h++) al4[t][h] = expf(e0[h] - m[h]) / (sum[h] + 1e-16f);
    }
    __syncthreads();
    // aggregate from LDS rows
    float ac[NH][2] = {};
#pragma unroll 4
    for (int j = 0; j < n; j++) {
        float4 al = *(const float4*)al4[j];
        float xv0 = bf16_to_f32(xs[j][t]);
        float xv1 = (t < FIN - 64) ? bf16_to_f32(xs[j][64 + t]) : 0.f;
        ac[0][0] += al.x * xv0; ac[0][1] += al.x * xv1;
        ac[1][0] += al.y * xv0; ac[1][1] += al.y * xv1;
        ac[2][0] += al.z * xv0; ac[2][1] += al.z * xv1;
        ac[3][0] += al.w * xv0; ac[3][1] += al.w * xv1;
    }
#pragma unroll
    for (int h = 0; h < NH; h++) {
        size_t base = ((size_t)d * NH + h) * KL1;
        aggXhi[base + t] = f32_to_bf16(ac[h][0]);
        if (t < 32) {  // k in [64,96): data for t<6, zero pad for 6<=t<32
            float v1 = (t < FIN - 64) ? ac[h][1] : 0.f;
            aggXhi[base + 64 + t] = f32_to_bf16(v1);
        }
    }
}

// ---------------- MFMA GEMM layer 1 (global_load_lds staging, single-term): K=96 per head ----------
__global__ __launch_bounds__(256) void k_gemm_l1(const unsigned short* __restrict__ aggXhi,
                                                 const unsigned short* __restrict__ W1t,
                                                 const float* __restrict__ b1,
                                                 unsigned short* __restrict__ x2hi) {
    __shared__ unsigned short As[128 * 32];
    __shared__ unsigned short Bs[128 * 32];
    int t = threadIdx.x;
    int n0 = blockIdx.x * 128;
    int cb = blockIdx.y * 128;       // col within head's 256
    int h  = blockIdx.z;
    int lane = t & 63, wave = t >> 6, quad = lane >> 4, l16 = lane & 15;
    int wr = (wave & 1) * 64, wc = (wave >> 1) * 64;
    int f0 = t, f1 = t + 256;
    int ra0 = n0 + (f0 >> 2); if (ra0 >= NN) ra0 = NN - 1;
    int ra1 = n0 + (f1 >> 2); if (ra1 >= NN) ra1 = NN - 1;
    const unsigned short* ga0 = aggXhi + ((size_t)ra0 * NH + h) * KL1 + (f0 & 3) * 8;
    const unsigned short* ga1 = aggXhi + ((size_t)ra1 * NH + h) * KL1 + (f1 & 3) * 8;
    const unsigned short* gb0 = W1t + (size_t)(h * 256 + cb + (f0 >> 2)) * KL1 + (f0 & 3) * 8;
    const unsigned short* gb1 = W1t + (size_t)(h * 256 + cb + (f1 >> 2)) * KL1 + (f1 & 3) * 8;
    unsigned short* la0 = As + f0 * 8;
    unsigned short* la1 = As + f1 * 8;
    unsigned short* lb0 = Bs + f0 * 8;
    unsigned short* lb1 = Bs + f1 * 8;
    f32x4 acc[4][4] = {};
    for (int kc = 0; kc < 3; kc++) {
        cp16(ga0 + kc * 32, la0);
        cp16(ga1 + kc * 32, la1);
        cp16(gb0 + kc * 32, lb0);
        cp16(gb1 + kc * 32, lb1);
        __syncthreads();
        bf16x8 af[4], bf[4];
#pragma unroll
        for (int i = 0; i < 4; i++) af[i] = *(const bf16x8*)&As[(wr + i * 16 + l16) * 32 + quad * 8];
#pragma unroll
        for (int j = 0; j < 4; j++) bf[j] = *(const bf16x8*)&Bs[(wc + j * 16 + l16) * 32 + quad * 8];
#pragma unroll
        for (int i = 0; i < 4; i++)
#pragma unroll
            for (int j = 0; j < 4; j++)
                acc[i][j] = __builtin_amdgcn_mfma_f32_16x16x32_bf16(af[i], bf[j], acc[i][j], 0, 0, 0);
        __syncthreads();
    }
#pragma unroll
    for (int i = 0; i < 4; i++)
#pragma unroll
        for (int j = 0; j < 4; j++) {
            int colg = h * 256 + cb + wc + j * 16 + l16;
            float bb = b1[colg];
#pragma unroll
            for (int reg = 0; reg < 4; reg++) {
                int r = n0 + wr + i * 16 + quad * 4 + reg;
                if (r >= NN) continue;
                float v = fmaxf(acc[i][j][reg] + bb, 0.f);
                x2hi[(size_t)r * D1 + colg] = f32_to_bf16(v);
            }
        }
}

// ---------------- MFMA GEMM layer 2: BM=64, BN=128, 128 thr (2 waves), grid (157,2) ----------------
// full K=1024; fused epilogue writes bf16 h2 + attention dots as2/ad2
__global__ __launch_bounds__(128) void k_gemm2(const unsigned short* __restrict__ x2hi,
                                               const unsigned short* __restrict__ W2t,
                                               const float* __restrict__ asrc,
                                               const float* __restrict__ adst,
                                               unsigned short* __restrict__ h2bf,
                                               float* __restrict__ as2,
                                               float* __restrict__ ad2) {
    __shared__ unsigned short As[64 * 32];
    __shared__ unsigned short Bs[128 * 32];
    int t = threadIdx.x;
    int n0 = blockIdx.x * 64;
    int cb = blockIdx.y * 128;
    int lane = t & 63, wave = t >> 6, quad = lane >> 4, l16 = lane & 15;
    int wc = wave * 64;
    // A: 256 chunks (64 rows x 4), 2 per thread
    int fa0 = t, fa1 = t + 128;
    int raa0 = n0 + (fa0 >> 2); if (raa0 >= NN) raa0 = NN - 1;
    int raa1 = n0 + (fa1 >> 2); if (raa1 >= NN) raa1 = NN - 1;
    const unsigned short* ga0 = x2hi + (size_t)raa0 * D1 + (fa0 & 3) * 8;
    const unsigned short* ga1 = x2hi + (size_t)raa1 * D1 + (fa1 & 3) * 8;
    unsigned short* la0 = As + fa0 * 8;
    unsigned short* la1 = As + fa1 * 8;
    // B: 512 chunks (128 cols x 4), 4 per thread
    const unsigned short* gb[4];
    unsigned short* lb[4];
#pragma unroll
    for (int q = 0; q < 4; q++) {
        int f = t + q * 128;
        gb[q] = W2t + (size_t)(cb + (f >> 2)) * 1024 + (f & 3) * 8;
        lb[q] = Bs + f * 8;
    }
    f32x4 acc[4][4] = {};
    for (int kc = 0; kc < 32; kc++) {
        cp16(ga0 + kc * 32, la0);
        cp16(ga1 + kc * 32, la1);
#pragma unroll
        for (int q = 0; q < 4; q++) cp16(gb[q] + kc * 32, lb[q]);
        __syncthreads();
        bf16x8 af[4], bf[4];
#pragma unroll
        for (int i = 0; i < 4; i++) af[i] = *(const bf16x8*)&As[(i * 16 + l16) * 32 + quad * 8];
#pragma unroll
        for (int j = 0; j < 4; j++) bf[j] = *(const bf16x8*)&Bs[(wc + j * 16 + l16) * 32 + quad * 8];
#pragma unroll
        for (int i = 0; i < 4; i++)
#pragma unroll
            for (int j = 0; j < 4; j++)
                acc[i][j] = __builtin_amdgcn_mfma_f32_16x16x32_bf16(af[i], bf[j], acc[i][j], 0, 0, 0);
        __syncthreads();
    }
    // epilogue: bf16 store + attention partial dots
    float a2[4], d2[4];
#pragma unroll
    for (int j = 0; j < 4; j++) {
        int c = cb + wc + j * 16 + l16;
        a2[j] = asrc[c];
        d2[j] = adst[c];
    }
    float asp[4][4] = {}, adp[4][4] = {};
#pragma unroll
    for (int i = 0; i < 4; i++)
#pragma unroll
        for (int j = 0; j < 4; j++) {
            int c = cb + wc + j * 16 + l16;
#pragma unroll
            for (int reg = 0; reg < 4; reg++) {
                int r = n0 + i * 16 + quad * 4 + reg;
                float v = acc[i][j][reg];
                if (r < NN) h2bf[(size_t)r * HIDC + c] = f32_to_bf16(v);
                asp[i][reg] += v * a2[j];
                adp[i][reg] += v * d2[j];
            }
        }
#pragma unroll
    for (int mask = 1; mask < 16; mask <<= 1)
#pragma unroll
        for (int i = 0; i < 4; i++)
#pragma unroll
            for (int reg = 0; reg < 4; reg++) {
                asp[i][reg] += __shfl_xor(asp[i][reg], mask);
                adp[i][reg] += __shfl_xor(adp[i][reg], mask);
            }
    if (l16 == 0) {
#pragma unroll
        for (int i = 0; i < 4; i++)
#pragma unroll
            for (int reg = 0; reg < 4; reg++) {
                int r = n0 + i * 16 + quad * 4 + reg;
                if (r < NN) {
                    atomicAdd(&as2[r], asp[i][reg]);
                    atomicAdd(&ad2[r], adp[i][reg]);
                }
            }
    }
}

// ---------------- fused softmax(H=1) + layer-2 aggregation + bucketed pool (deg<=64) ------------
__global__ __launch_bounds__(256) void k_sm_aggr2(const int* __restrict__ cnt,
                                                  const int* __restrict__ ssrc,
                                                  const float* __restrict__ as,
                                                  const float* __restrict__ ad,
                                                  const unsigned short* __restrict__ h2bf,
                                                  const float* __restrict__ b,
                                                  float* __restrict__ pooled32) {
    int d = blockIdx.x, t = threadIdx.x, lane = t & 63;
    int n = cnt[d]; if (n > BCAP) n = BCAP;
    float adv = ad[d];
    bool v0 = lane < n;
    int s0 = v0 ? ssrc[d * BCAP + lane] : 0;
    float e0 = v0 ? leaky(as[s0] + adv) : -1e30f;
    float m = e0;
    for (int off = 32; off > 0; off >>= 1) m = fmaxf(m, __shfl_xor(m, off));
    float sum = v0 ? expf(e0 - m) : 0.f;
    for (int off = 32; off > 0; off >>= 1) sum += __shfl_xor(sum, off);
    float inv = 1.0f / (sum + 1e-16f);
    __shared__ float als[64];
    __shared__ int   sid[64];
    if (v0) { sid[lane] = s0; als[lane] = expf(e0 - m) * inv; }   // all waves write identical values
    __syncthreads();
    float acc = 0.f;
#pragma unroll 4
    for (int j = 0; j < n; j++)
        acc += als[j] * bf16_to_f32(h2bf[(size_t)sid[j] * HIDC + t]);
    float v = fmaxf(acc + b[t], 0.f);
    atomicAdd(&pooled32[(d & (NPB - 1)) * HIDC + t], v);
}

// ---------------- MLP head: bucket-reduce + 256 -> 128 (gelu exact) -> 1 ----------------
__global__ __launch_bounds__(128) void k_mlp(const float* __restrict__ pooled32,
                                             const float* __restrict__ Wv1,
                                             const float* __restrict__ bv1,
                                             const float* __restrict__ Wv2,
                                             const float* __restrict__ bv2,
                                             float* __restrict__ out) {
    int j = threadIdx.x;
    __shared__ float ps[256];
    for (int c = j; c < HIDC; c += 128) {
        float s = 0.f;
        for (int bkt = 0; bkt < NPB; bkt++) s += pooled32[bkt * HIDC + c];
        ps[c] = s;
    }
    __syncthreads();
    float s = bv1[j];
    const float invn = 1.0f / (float)NN;
    for (int c = 0; c < HIDC; c++)
        s += (ps[c] * invn) * Wv1[c * 128 + j];
    float g = 0.5f * s * (1.0f + erff(s * 0.70710678118654752f));
    float v = g * Wv2[j];
    __shared__ float red[128];
    red[j] = v;
    __syncthreads();
    for (int off = 64; off > 0; off >>= 1) {
        if (j < off) red[j] += red[j + off];
        __syncthreads();
    }
    if (j == 0) out[0] = red[0] + bv2[0];
}

extern "C" void kernel_launch(void* const* d_in, const int* in_sizes, int n_in,
                              void* d_out, int out_size, void* d_ws, size_t ws_size,
                              hipStream_t stream) {
    const float* x_in  = (const float*)d_in[0];
    const int*   ei    = (const int*)d_in[1];
    // d_in[2] = edge_attr: ignored (GATConv has no edge_dim)
    const float* W1    = (const float*)d_in[3];
    const float* asrc1 = (const float*)d_in[4];
    const float* adst1 = (const float*)d_in[5];
    const float* b1    = (const float*)d_in[6];
    const float* W2    = (const float*)d_in[7];
    const float* asrc2 = (const float*)d_in[8];
    const float* adst2 = (const float*)d_in[9];
    const float* b2    = (const float*)d_in[10];
    const float* Wv1   = (const float*)d_in[11];
    const float* bv1   = (const float*)d_in[12];
    const float* Wv2   = (const float*)d_in[13];
    const float* bv2   = (const float*)d_in[14];
    float* out = (float*)d_out;

    char* w = (char*)d_ws;
    auto alloc = [&](size_t bytes) { char* p = w; w += (bytes + 255) & ~(size_t)255; return p; };
    unsigned short* x2hi   = (unsigned short*)alloc(2ull * NN * D1);           // 20.5 MB
    unsigned short* aggXhi = (unsigned short*)alloc(2ull * NN * NH * KL1);     // 7.68 MB
    unsigned short* h2bf = (unsigned short*)alloc(2ull * NN * HIDC);           // 5.12 MB
    unsigned short* xb   = (unsigned short*)alloc(2ull * NN * FIN);            // 1.4 MB
    unsigned short* W2t  = (unsigned short*)alloc(2ull * 256 * 1024);          // 0.52 MB
    unsigned short* W1t  = (unsigned short*)alloc(2ull * NH * 256 * KL1);      // 0.20 MB
    float* was1   = (float*)alloc(sizeof(float) * NH * FIN);
    float* wad1   = (float*)alloc(sizeof(float) * NH * FIN);
    int*   ssrc   = (int*)alloc(sizeof(int) * NN * BCAP);                      // 2.56 MB
    // single zero-init region: cnt | pooled32 | as2 | ad2 (one memset)
    char*  zbase  = alloc(NN * 4 + NPB * HIDC * 4 + NN * 4 + NN * 4);
    int*   cnt      = (int*)zbase;
    float* pooled32 = (float*)(zbase + NN * 4);
    float* as2      = (float*)(zbase + NN * 4 + NPB * HIDC * 4);
    float* ad2      = (float*)(zbase + NN * 4 + NPB * HIDC * 4 + NN * 4);

    hipMemsetAsync(zbase, 0, NN * 4 + NPB * HIDC * 4 + NN * 4 + NN * 4, stream);

    // fused prep: weight conversions + was/wad + x->bf16 + bucket scatter
    k_prep<<<1024 + KL1 + FIN + 40 + 665, 256, 0, stream>>>(
        W2, W2t, W1, W1t, asrc1, adst1, was1, wad1, x_in, xb, ei, cnt, ssrc);

    // ---- layer 1 (attention logits computed in-kernel from staged LDS rows) ----
    k_sm_aggX<<<NN, 64, 0, stream>>>(cnt, ssrc, was1, wad1, xb, aggXhi);
    {
        dim3 g((NN + 127) / 128, 2, NH);
        k_gemm_l1<<<g, 256, 0, stream>>>(aggXhi, W1t, b1, x2hi);
    }

    // ---- layer 2 (att_h2 fused into gemm2 epilogue; BM=64 grid for full-CU coverage) ----
    {
        dim3 g((NN + 63) / 64, 2);
        k_gemm2<<<g, 128, 0, stream>>>(x2hi, W2t, asrc2, adst2, h2bf, as2, ad2);
    }
    k_sm_aggr2<<<NN, 256, 0, stream>>>(cnt, ssrc, as2, ad2, h2bf, b2, pooled32);

    k_mlp<<<1, 128, 0, stream>>>(pooled32, Wv1, bv1, Wv2, bv2, out);
}

// Round 13
// 210.579 us; speedup vs baseline: 1.1166x; 1.1166x over previous
//
#include <hip/hip_runtime.h>
#include <math.h>

#define NN   10000          // nodes
#define NE   160000         // raw edges
#define NET  (NE + NN)      // edges + self loops = 170000
#define FIN  70
#define HIDC 256
#define NH   4
#define D1   1024           // NH*HIDC
#define SLOPE 0.2f
#define KL1  96             // K for layer-1 GEMM (70 padded to 96)
#define NPB  32             // pooling buckets
#define BCAP 64             // per-dst edge bucket capacity (deg mean 17, P(>63)~1e-15)

typedef float f32x4 __attribute__((ext_vector_type(4)));
typedef short bf16x8 __attribute__((ext_vector_type(8)));

__device__ __forceinline__ unsigned short f32_to_bf16(float f) {
    unsigned int u = __float_as_uint(f);
    unsigned int r = u + 0x7fffu + ((u >> 16) & 1u);   // round-to-nearest-even
    return (unsigned short)(r >> 16);
}
__device__ __forceinline__ float bf16_to_f32(unsigned short h) {
    return __uint_as_float(((unsigned int)h) << 16);
}
__device__ __forceinline__ float leaky(float e) { return (e > 0.f) ? e : SLOPE * e; }

// async 16B global->LDS DMA (m97-verified path; LDS dest = wave base + lane*16)
__device__ __forceinline__ void cp16(const unsigned short* g, unsigned short* l) {
    __builtin_amdgcn_global_load_lds((const __attribute__((address_space(1))) unsigned int*)g,
                                     (__attribute__((address_space(3))) unsigned int*)l,
                                     16, 0, 0);
}

// ---------------- fused prep: W2 conv | W1 conv | was/wad | x->bf16 | bucket scatter ----------------
// blocks: [0,1024) W2 ; [1024,1120) W1 ; [1120,1190) was/wad ; [1190,1230) xb ; [1230,1895) scatter
__global__ __launch_bounds__(256) void k_prep(const float* __restrict__ W2,
                                              unsigned short* __restrict__ W2t,
                                              const float* __restrict__ W1,
                                              unsigned short* __restrict__ W1t,
                                              const float* __restrict__ asrc,
                                              const float* __restrict__ adst,
                                              float* __restrict__ was,
                                              float* __restrict__ wad,
                                              const float* __restrict__ x,
                                              unsigned short* __restrict__ xb,
                                              const int* __restrict__ ei,
                                              int* __restrict__ cnt,
                                              int* __restrict__ ssrc) {
    int b = blockIdx.x, t = threadIdx.x;
    if (b < 1024) {
        int kk = b, n = t;
        W2t[(size_t)n * 1024 + kk] = f32_to_bf16(W2[(size_t)kk * HIDC + n]);
    } else if (b < 1024 + KL1) {
        int kk = b - 1024, n = t;
#pragma unroll
        for (int h = 0; h < NH; h++) {
            float w = (kk < FIN) ? W1[(size_t)kk * D1 + h * 256 + n] : 0.f;
            W1t[((size_t)(h * 256 + n)) * KL1 + kk] = f32_to_bf16(w);
        }
    } else if (b < 1024 + KL1 + FIN) {
        int k = b - 1024 - KL1;
        __shared__ float rs[256], rd[256];
#pragma unroll
        for (int h = 0; h < NH; h++) {
            float wv = W1[(size_t)k * D1 + h * 256 + t];
            rs[t] = wv * asrc[h * 256 + t];
            rd[t] = wv * adst[h * 256 + t];
            __syncthreads();
            for (int off = 128; off > 0; off >>= 1) {
                if (t < off) { rs[t] += rs[t + off]; rd[t] += rd[t + off]; }
                __syncthreads();
            }
            if (t == 0) { was[h * FIN + k] = rs[0]; wad[h * FIN + k] = rd[0]; }
            __syncthreads();
        }
    } else if (b < 1024 + KL1 + FIN + 40) {
        int b2 = b - 1024 - KL1 - FIN;                 // 0..39, 17500 elems each
        size_t base = (size_t)b2 * 17500;
        for (int i = t; i < 17500; i += 256)
            xb[base + i] = f32_to_bf16(x[base + i]);
    } else {
        int e = (b - 1024 - KL1 - FIN - 40) * 256 + t;
        if (e < NET) {
            int src, dst;
            if (e < NE) { src = ei[e]; dst = ei[NE + e]; }
            else        { src = e - NE; dst = src; }
            int pos = atomicAdd(&cnt[dst], 1);
            if (pos < BCAP) ssrc[dst * BCAP + pos] = src;
        }
    }
}

// ---------------- per-node attention logits from x ----------------
__global__ __launch_bounds__(256) void k_att_x(const float* __restrict__ x,
                                               const float* __restrict__ was,
                                               const float* __restrict__ wad,
                                               float* __restrict__ asn,
                                               float* __restrict__ adn) {
    __shared__ float xs[64][71];
    int t = threadIdx.x;
    int n0 = blockIdx.x * 64;
    for (int i = t; i < 64 * FIN; i += 256) {
        int r = i / FIN, k = i % FIN;
        int n = n0 + r;
        xs[r][k] = (n < NN) ? x[(size_t)n * FIN + k] : 0.f;
    }
    __syncthreads();
    if (t >= 64) return;
    int n = n0 + t;
    if (n >= NN) return;
    float a[NH] = {}, d[NH] = {};
    for (int k = 0; k < FIN; k++) {
        float xv = xs[t][k];
#pragma unroll
        for (int h = 0; h < NH; h++) {
            a[h] += xv * was[h * FIN + k];
            d[h] += xv * wad[h * FIN + k];
        }
    }
#pragma unroll
    for (int h = 0; h < NH; h++) { asn[n * NH + h] = a[h]; adn[n * NH + h] = d[h]; }
}

// ---------------- fused softmax(H=4) + layer-1 aggregation (bucket CSR, deg<=64) ----------------
__global__ __launch_bounds__(64) void k_sm_aggX(const int* __restrict__ cnt,
                                                const int* __restrict__ ssrc,
                                                const float* __restrict__ as,
                                                const float* __restrict__ ad,
                                                const unsigned short* __restrict__ xb,
                                                unsigned short* __restrict__ aggXhi) {
    int d = blockIdx.x, t = threadIdx.x;
    int n = cnt[d]; if (n > BCAP) n = BCAP;
    float4 adv = *(const float4*)&ad[d * NH];
    bool v0 = t < n;
    int s0 = 0;
    float e0[NH];
    if (v0) {
        s0 = ssrc[d * BCAP + t];
        float4 a4 = *(const float4*)&as[s0 * NH];
        e0[0] = leaky(a4.x + adv.x); e0[1] = leaky(a4.y + adv.y);
        e0[2] = leaky(a4.z + adv.z); e0[3] = leaky(a4.w + adv.w);
    } else { e0[0] = e0[1] = e0[2] = e0[3] = -1e30f; }
    float m[NH] = {e0[0], e0[1], e0[2], e0[3]};
#pragma unroll
    for (int h = 0; h < NH; h++)
        for (int off = 32; off > 0; off >>= 1)
            m[h] = fmaxf(m[h], __shfl_xor(m[h], off));
    float sum[NH];
#pragma unroll
    for (int h = 0; h < NH; h++) sum[h] = v0 ? expf(e0[h] - m[h]) : 0.f;
#pragma unroll
    for (int h = 0; h < NH; h++)
        for (int off = 32; off > 0; off >>= 1)
            sum[h] += __shfl_xor(sum[h], off);
    __shared__ float al4[64][4];
    __shared__ int   sid[64];
    if (v0) {
        sid[t] = s0;
#pragma unroll
        for (int h = 0; h < NH; h++) al4[t][h] = expf(e0[h] - m[h]) / (sum[h] + 1e-16f);
    }
    __syncthreads();
    float ac[NH][2] = {};
#pragma unroll 4
    for (int j = 0; j < n; j++) {
        int s = sid[j];
        float4 al = *(const float4*)al4[j];
        float xv0 = bf16_to_f32(xb[(size_t)s * FIN + t]);
        float xv1 = (t < FIN - 64) ? bf16_to_f32(xb[(size_t)s * FIN + 64 + t]) : 0.f;
        ac[0][0] += al.x * xv0; ac[0][1] += al.x * xv1;
        ac[1][0] += al.y * xv0; ac[1][1] += al.y * xv1;
        ac[2][0] += al.z * xv0; ac[2][1] += al.z * xv1;
        ac[3][0] += al.w * xv0; ac[3][1] += al.w * xv1;
    }
#pragma unroll
    for (int h = 0; h < NH; h++) {
        size_t base = ((size_t)d * NH + h) * KL1;
        aggXhi[base + t] = f32_to_bf16(ac[h][0]);
        if (t < 32) {  // k in [64,96): data for t<6, zero pad for 6<=t<32
            float v1 = (t < FIN - 64) ? ac[h][1] : 0.f;
            aggXhi[base + 64 + t] = f32_to_bf16(v1);
        }
    }
}

// ---------------- MFMA GEMM layer 1 (global_load_lds staging, single-term): K=96 per head ----------
__global__ __launch_bounds__(256) void k_gemm_l1(const unsigned short* __restrict__ aggXhi,
                                                 const unsigned short* __restrict__ W1t,
                                                 const float* __restrict__ b1,
                                                 unsigned short* __restrict__ x2hi) {
    __shared__ unsigned short As[128 * 32];
    __shared__ unsigned short Bs[128 * 32];
    int t = threadIdx.x;
    int n0 = blockIdx.x * 128;
    int cb = blockIdx.y * 128;       // col within head's 256
    int h  = blockIdx.z;
    int lane = t & 63, wave = t >> 6, quad = lane >> 4, l16 = lane & 15;
    int wr = (wave & 1) * 64, wc = (wave >> 1) * 64;
    int f0 = t, f1 = t + 256;
    int ra0 = n0 + (f0 >> 2); if (ra0 >= NN) ra0 = NN - 1;
    int ra1 = n0 + (f1 >> 2); if (ra1 >= NN) ra1 = NN - 1;
    const unsigned short* ga0 = aggXhi + ((size_t)ra0 * NH + h) * KL1 + (f0 & 3) * 8;
    const unsigned short* ga1 = aggXhi + ((size_t)ra1 * NH + h) * KL1 + (f1 & 3) * 8;
    const unsigned short* gb0 = W1t + (size_t)(h * 256 + cb + (f0 >> 2)) * KL1 + (f0 & 3) * 8;
    const unsigned short* gb1 = W1t + (size_t)(h * 256 + cb + (f1 >> 2)) * KL1 + (f1 & 3) * 8;
    unsigned short* la0 = As + f0 * 8;
    unsigned short* la1 = As + f1 * 8;
    unsigned short* lb0 = Bs + f0 * 8;
    unsigned short* lb1 = Bs + f1 * 8;
    f32x4 acc[4][4] = {};
    for (int kc = 0; kc < 3; kc++) {
        cp16(ga0 + kc * 32, la0);
        cp16(ga1 + kc * 32, la1);
        cp16(gb0 + kc * 32, lb0);
        cp16(gb1 + kc * 32, lb1);
        __syncthreads();
        bf16x8 af[4], bf[4];
#pragma unroll
        for (int i = 0; i < 4; i++) af[i] = *(const bf16x8*)&As[(wr + i * 16 + l16) * 32 + quad * 8];
#pragma unroll
        for (int j = 0; j < 4; j++) bf[j] = *(const bf16x8*)&Bs[(wc + j * 16 + l16) * 32 + quad * 8];
#pragma unroll
        for (int i = 0; i < 4; i++)
#pragma unroll
            for (int j = 0; j < 4; j++)
                acc[i][j] = __builtin_amdgcn_mfma_f32_16x16x32_bf16(af[i], bf[j], acc[i][j], 0, 0, 0);
        __syncthreads();
    }
#pragma unroll
    for (int i = 0; i < 4; i++)
#pragma unroll
        for (int j = 0; j < 4; j++) {
            int colg = h * 256 + cb + wc + j * 16 + l16;
            float bb = b1[colg];
#pragma unroll
            for (int reg = 0; reg < 4; reg++) {
                int r = n0 + wr + i * 16 + quad * 4 + reg;
                if (r >= NN) continue;
                float v = fmaxf(acc[i][j][reg] + bb, 0.f);
                x2hi[(size_t)r * D1 + colg] = f32_to_bf16(v);
            }
        }
}

// ---------------- MFMA GEMM layer 2: BM=64, BN=128, 128 thr (2 waves), grid (157,2) ----------------
// full K=1024; fused epilogue writes bf16 h2 + attention dots as2/ad2
__global__ __launch_bounds__(128) void k_gemm2(const unsigned short* __restrict__ x2hi,
                                               const unsigned short* __restrict__ W2t,
                                               const float* __restrict__ asrc,
                                               const float* __restrict__ adst,
                                               unsigned short* __restrict__ h2bf,
                                               float* __restrict__ as2,
                                               float* __restrict__ ad2) {
    __shared__ unsigned short As[64 * 32];
    __shared__ unsigned short Bs[128 * 32];
    int t = threadIdx.x;
    int n0 = blockIdx.x * 64;
    int cb = blockIdx.y * 128;
    int lane = t & 63, wave = t >> 6, quad = lane >> 4, l16 = lane & 15;
    int wc = wave * 64;
    int fa0 = t, fa1 = t + 128;
    int raa0 = n0 + (fa0 >> 2); if (raa0 >= NN) raa0 = NN - 1;
    int raa1 = n0 + (fa1 >> 2); if (raa1 >= NN) raa1 = NN - 1;
    const unsigned short* ga0 = x2hi + (size_t)raa0 * D1 + (fa0 & 3) * 8;
    const unsigned short* ga1 = x2hi + (size_t)raa1 * D1 + (fa1 & 3) * 8;
    unsigned short* la0 = As + fa0 * 8;
    unsigned short* la1 = As + fa1 * 8;
    const unsigned short* gb[4];
    unsigned short* lb[4];
#pragma unroll
    for (int q = 0; q < 4; q++) {
        int f = t + q * 128;
        gb[q] = W2t + (size_t)(cb + (f >> 2)) * 1024 + (f & 3) * 8;
        lb[q] = Bs + f * 8;
    }
    f32x4 acc[4][4] = {};
    for (int kc = 0; kc < 32; kc++) {
        cp16(ga0 + kc * 32, la0);
        cp16(ga1 + kc * 32, la1);
#pragma unroll
        for (int q = 0; q < 4; q++) cp16(gb[q] + kc * 32, lb[q]);
        __syncthreads();
        bf16x8 af[4], bf[4];
#pragma unroll
        for (int i = 0; i < 4; i++) af[i] = *(const bf16x8*)&As[(i * 16 + l16) * 32 + quad * 8];
#pragma unroll
        for (int j = 0; j < 4; j++) bf[j] = *(const bf16x8*)&Bs[(wc + j * 16 + l16) * 32 + quad * 8];
#pragma unroll
        for (int i = 0; i < 4; i++)
#pragma unroll
            for (int j = 0; j < 4; j++)
                acc[i][j] = __builtin_amdgcn_mfma_f32_16x16x32_bf16(af[i], bf[j], acc[i][j], 0, 0, 0);
        __syncthreads();
    }
    float a2[4], d2[4];
#pragma unroll
    for (int j = 0; j < 4; j++) {
        int c = cb + wc + j * 16 + l16;
        a2[j] = asrc[c];
        d2[j] = adst[c];
    }
    float asp[4][4] = {}, adp[4][4] = {};
#pragma unroll
    for (int i = 0; i < 4; i++)
#pragma unroll
        for (int j = 0; j < 4; j++) {
            int c = cb + wc + j * 16 + l16;
#pragma unroll
            for (int reg = 0; reg < 4; reg++) {
                int r = n0 + i * 16 + quad * 4 + reg;
                float v = acc[i][j][reg];
                if (r < NN) h2bf[(size_t)r * HIDC + c] = f32_to_bf16(v);
                asp[i][reg] += v * a2[j];
                adp[i][reg] += v * d2[j];
            }
        }
#pragma unroll
    for (int mask = 1; mask < 16; mask <<= 1)
#pragma unroll
        for (int i = 0; i < 4; i++)
#pragma unroll
            for (int reg = 0; reg < 4; reg++) {
                asp[i][reg] += __shfl_xor(asp[i][reg], mask);
                adp[i][reg] += __shfl_xor(adp[i][reg], mask);
            }
    if (l16 == 0) {
#pragma unroll
        for (int i = 0; i < 4; i++)
#pragma unroll
            for (int reg = 0; reg < 4; reg++) {
                int r = n0 + i * 16 + quad * 4 + reg;
                if (r < NN) {
                    atomicAdd(&as2[r], asp[i][reg]);
                    atomicAdd(&ad2[r], adp[i][reg]);
                }
            }
    }
}

// ---------------- fused softmax(H=1) + layer-2 aggregation + bucketed pool (deg<=64) ------------
__global__ __launch_bounds__(256) void k_sm_aggr2(const int* __restrict__ cnt,
                                                  const int* __restrict__ ssrc,
                                                  const float* __restrict__ as,
                                                  const float* __restrict__ ad,
                                                  const unsigned short* __restrict__ h2bf,
                                                  const float* __restrict__ b,
                                                  float* __restrict__ pooled32) {
    int d = blockIdx.x, t = threadIdx.x, lane = t & 63;
    int n = cnt[d]; if (n > BCAP) n = BCAP;
    float adv = ad[d];
    bool v0 = lane < n;
    int s0 = v0 ? ssrc[d * BCAP + lane] : 0;
    float e0 = v0 ? leaky(as[s0] + adv) : -1e30f;
    float m = e0;
    for (int off = 32; off > 0; off >>= 1) m = fmaxf(m, __shfl_xor(m, off));
    float sum = v0 ? expf(e0 - m) : 0.f;
    for (int off = 32; off > 0; off >>= 1) sum += __shfl_xor(sum, off);
    float inv = 1.0f / (sum + 1e-16f);
    __shared__ float als[64];
    __shared__ int   sid[64];
    if (v0) { sid[lane] = s0; als[lane] = expf(e0 - m) * inv; }   // all waves write identical values
    __syncthreads();
    float acc = 0.f;
#pragma unroll 4
    for (int j = 0; j < n; j++)
        acc += als[j] * bf16_to_f32(h2bf[(size_t)sid[j] * HIDC + t]);
    float v = fmaxf(acc + b[t], 0.f);
    atomicAdd(&pooled32[(d & (NPB - 1)) * HIDC + t], v);
}

// ---------------- MLP head: bucket-reduce + 256 -> 128 (gelu exact) -> 1 ----------------
__global__ __launch_bounds__(128) void k_mlp(const float* __restrict__ pooled32,
                                             const float* __restrict__ Wv1,
                                             const float* __restrict__ bv1,
                                             const float* __restrict__ Wv2,
                                             const float* __restrict__ bv2,
                                             float* __restrict__ out) {
    int j = threadIdx.x;
    __shared__ float ps[256];
    for (int c = j; c < HIDC; c += 128) {
        float s = 0.f;
        for (int bkt = 0; bkt < NPB; bkt++) s += pooled32[bkt * HIDC + c];
        ps[c] = s;
    }
    __syncthreads();
    float s = bv1[j];
    const float invn = 1.0f / (float)NN;
    for (int c = 0; c < HIDC; c++)
        s += (ps[c] * invn) * Wv1[c * 128 + j];
    float g = 0.5f * s * (1.0f + erff(s * 0.70710678118654752f));
    float v = g * Wv2[j];
    __shared__ float red[128];
    red[j] = v;
    __syncthreads();
    for (int off = 64; off > 0; off >>= 1) {
        if (j < off) red[j] += red[j + off];
        __syncthreads();
    }
    if (j == 0) out[0] = red[0] + bv2[0];
}

extern "C" void kernel_launch(void* const* d_in, const int* in_sizes, int n_in,
                              void* d_out, int out_size, void* d_ws, size_t ws_size,
                              hipStream_t stream) {
    const float* x_in  = (const float*)d_in[0];
    const int*   ei    = (const int*)d_in[1];
    // d_in[2] = edge_attr: ignored (GATConv has no edge_dim)
    const float* W1    = (const float*)d_in[3];
    const float* asrc1 = (const float*)d_in[4];
    const float* adst1 = (const float*)d_in[5];
    const float* b1    = (const float*)d_in[6];
    const float* W2    = (const float*)d_in[7];
    const float* asrc2 = (const float*)d_in[8];
    const float* adst2 = (const float*)d_in[9];
    const float* b2    = (const float*)d_in[10];
    const float* Wv1   = (const float*)d_in[11];
    const float* bv1   = (const float*)d_in[12];
    const float* Wv2   = (const float*)d_in[13];
    const float* bv2   = (const float*)d_in[14];
    float* out = (float*)d_out;

    char* w = (char*)d_ws;
    auto alloc = [&](size_t bytes) { char* p = w; w += (bytes + 255) & ~(size_t)255; return p; };
    unsigned short* x2hi   = (unsigned short*)alloc(2ull * NN * D1);           // 20.5 MB
    unsigned short* aggXhi = (unsigned short*)alloc(2ull * NN * NH * KL1);     // 7.68 MB
    unsigned short* h2bf = (unsigned short*)alloc(2ull * NN * HIDC);           // 5.12 MB
    unsigned short* xb   = (unsigned short*)alloc(2ull * NN * FIN);            // 1.4 MB
    unsigned short* W2t  = (unsigned short*)alloc(2ull * 256 * 1024);          // 0.52 MB
    unsigned short* W1t  = (unsigned short*)alloc(2ull * NH * 256 * KL1);      // 0.20 MB
    float* as1    = (float*)alloc(sizeof(float) * NN * NH);
    float* ad1    = (float*)alloc(sizeof(float) * NN * NH);
    float* was1   = (float*)alloc(sizeof(float) * NH * FIN);
    float* wad1   = (float*)alloc(sizeof(float) * NH * FIN);
    int*   ssrc   = (int*)alloc(sizeof(int) * NN * BCAP);                      // 2.56 MB
    // single zero-init region: cnt | pooled32 | as2 | ad2 (one memset)
    char*  zbase  = alloc(NN * 4 + NPB * HIDC * 4 + NN * 4 + NN * 4);
    int*   cnt      = (int*)zbase;
    float* pooled32 = (float*)(zbase + NN * 4);
    float* as2      = (float*)(zbase + NN * 4 + NPB * HIDC * 4);
    float* ad2      = (float*)(zbase + NN * 4 + NPB * HIDC * 4 + NN * 4);

    hipMemsetAsync(zbase, 0, NN * 4 + NPB * HIDC * 4 + NN * 4 + NN * 4, stream);

    // fused prep: weight conversions + was/wad + x->bf16 + bucket scatter
    k_prep<<<1024 + KL1 + FIN + 40 + 665, 256, 0, stream>>>(
        W2, W2t, W1, W1t, asrc1, adst1, was1, wad1, x_in, xb, ei, cnt, ssrc);
    k_att_x<<<157, 256, 0, stream>>>(x_in, was1, wad1, as1, ad1);

    // ---- layer 1 ----
    k_sm_aggX<<<NN, 64, 0, stream>>>(cnt, ssrc, as1, ad1, xb, aggXhi);
    {
        dim3 g((NN + 127) / 128, 2, NH);
        k_gemm_l1<<<g, 256, 0, stream>>>(aggXhi, W1t, b1, x2hi);
    }

    // ---- layer 2 (att_h2 fused into gemm2 epilogue; BM=64 grid for full-CU coverage) ----
    {
        dim3 g((NN + 63) / 64, 2);
        k_gemm2<<<g, 128, 0, stream>>>(x2hi, W2t, asrc2, adst2, h2bf, as2, ad2);
    }
    k_sm_aggr2<<<NN, 256, 0, stream>>>(cnt, ssrc, as2, ad2, h2bf, b2, pooled32);

    k_mlp<<<1, 128, 0, stream>>>(pooled32, Wv1, bv1, Wv2, bv2, out);
}